// Round 1
// baseline (789.352 us; speedup 1.0000x reference)
//
#include <hip/hip_runtime.h>

#define HEADS 4
#define OUTF 64
#define INF 64
#define NB 16  // nodes per block in projection kernel

// --- detect whether edge_index arrived as int64 (odd dwords all zero) or int32 ---
__global__ __launch_bounds__(64) void detect_i64(const int* __restrict__ ei, int* __restrict__ flag) {
    if (threadIdx.x == 0) {
        int all0 = 1;
        #pragma unroll
        for (int i = 1; i < 64; i += 2) all0 &= (ei[i] == 0);
        *flag = all0;  // 1 -> int64 layout, 0 -> int32 layout
    }
}

// --- h[n,h,o] = sum_f x[n,f] * W[h,f,o]; s_src[n,h] = <h[n,h,:], a_src[h,:]>, same for dst ---
// block = 256 threads = 4 waves; wave w handles head w; lane = output feature o.
// Each thread keeps its W column (64 floats) in VGPRs; x row reads are wave-uniform (scalar loads).
__global__ __launch_bounds__(256) void proj_kernel(
    const float* __restrict__ x, const float* __restrict__ W,
    const float* __restrict__ a_src, const float* __restrict__ a_dst,
    float* __restrict__ h_ws, float* __restrict__ ssrc, float* __restrict__ sdst,
    int nNodes)
{
    const int tid  = threadIdx.x;
    const int head = tid >> 6;
    const int o    = tid & 63;

    float w[64];
    const float* Wp = W + (size_t)head * (INF * OUTF) + o;
    #pragma unroll
    for (int f = 0; f < 64; ++f) w[f] = Wp[f * OUTF];

    const float asrc = a_src[tid];  // a_src[head*64 + o] == a_src[tid]
    const float adst = a_dst[tid];

    const int n0 = blockIdx.x * NB;
    const int n1 = (n0 + NB < nNodes) ? (n0 + NB) : nNodes;
    for (int n = n0; n < n1; ++n) {
        const float* xr = x + (size_t)n * INF;  // wave-uniform address -> s_load
        float acc = 0.f;
        #pragma unroll
        for (int f = 0; f < 64; ++f) acc = fmaf(xr[f], w[f], acc);
        h_ws[(size_t)n * 256 + tid] = acc;

        float rs = acc * asrc;
        float rd = acc * adst;
        #pragma unroll
        for (int off = 32; off > 0; off >>= 1) {
            rs += __shfl_xor(rs, off);
            rd += __shfl_xor(rd, off);
        }
        if (o == 0) {
            ssrc[n * 4 + head] = rs;
            sdst[n * 4 + head] = rd;
        }
    }
}

// --- one wave per edge: w_h = exp(leakyrelu(s_src[src,h] + s_dst[dst,h]));
//     atomically accumulate unnormalized w_h * h[src,h,:] into out[dst,:] and w_h into denom[dst,h].
__global__ __launch_bounds__(256) void edge_scatter(
    const int* __restrict__ ei, const float* __restrict__ h_ws,
    const float* __restrict__ ssrc, const float* __restrict__ sdst,
    float* __restrict__ denom, float* __restrict__ out,
    const int* __restrict__ flag, int nEdges)
{
    const int wave = (int)((blockIdx.x * (unsigned)blockDim.x + threadIdx.x) >> 6);
    const int lane = threadIdx.x & 63;
    if (wave >= nEdges) return;

    int src, dst;
    if (*flag) {  // int64 layout: low dwords at even indices
        src = ei[2 * (size_t)wave];
        dst = ei[2 * ((size_t)nEdges + (size_t)wave)];
    } else {
        src = ei[wave];
        dst = ei[nEdges + wave];
    }

    float e0 = ssrc[src * 4 + 0] + sdst[dst * 4 + 0];
    float e1 = ssrc[src * 4 + 1] + sdst[dst * 4 + 1];
    float e2 = ssrc[src * 4 + 2] + sdst[dst * 4 + 2];
    float e3 = ssrc[src * 4 + 3] + sdst[dst * 4 + 3];
    e0 = e0 >= 0.f ? e0 : 0.2f * e0;
    e1 = e1 >= 0.f ? e1 : 0.2f * e1;
    e2 = e2 >= 0.f ? e2 : 0.2f * e2;
    e3 = e3 >= 0.f ? e3 : 0.2f * e3;
    // max-subtraction dropped: logits bounded (|e| <~ 5), cancels exactly in the final division
    const float w0 = __expf(e0);
    const float w1 = __expf(e1);
    const float w2 = __expf(e2);
    const float w3 = __expf(e3);

    const float* hsrc = h_ws + (size_t)src * 256;
    float*       odst = out  + (size_t)dst * 256;

    atomicAdd(&odst[0 * 64 + lane], w0 * hsrc[0 * 64 + lane]);
    atomicAdd(&odst[1 * 64 + lane], w1 * hsrc[1 * 64 + lane]);
    atomicAdd(&odst[2 * 64 + lane], w2 * hsrc[2 * 64 + lane]);
    atomicAdd(&odst[3 * 64 + lane], w3 * hsrc[3 * 64 + lane]);

    if (lane < 4) {
        float wl = (lane == 0) ? w0 : (lane == 1) ? w1 : (lane == 2) ? w2 : w3;
        atomicAdd(&denom[dst * 4 + lane], wl);
    }
}

// --- out[n, h*64+o] /= (denom[n,h] + 1e-16) ---
__global__ __launch_bounds__(256) void normalize_kernel(
    float* __restrict__ out, const float* __restrict__ denom, int total)
{
    int i = blockIdx.x * 256 + threadIdx.x;
    if (i >= total) return;
    int nh = i >> 6;  // n*4 + head
    out[i] = out[i] / (denom[nh] + 1e-16f);
}

extern "C" void kernel_launch(void* const* d_in, const int* in_sizes, int n_in,
                              void* d_out, int out_size, void* d_ws, size_t ws_size,
                              hipStream_t stream) {
    const float* x     = (const float*)d_in[0];
    const int*   ei    = (const int*)d_in[1];
    const float* W     = (const float*)d_in[2];
    const float* a_src = (const float*)d_in[3];
    const float* a_dst = (const float*)d_in[4];
    float*       out   = (float*)d_out;

    const int N = in_sizes[0] / INF;   // 50000
    const int E = in_sizes[1] / 2;     // 800000 (element count is 2E for either int width)

    // workspace layout (bytes): h[N*256] | ssrc[N*4] | sdst[N*4] | denom[N*4] | flag
    float* h_ws  = (float*)d_ws;
    float* ssrc  = h_ws + (size_t)N * 256;
    float* sdst  = ssrc + (size_t)N * 4;
    float* denom = sdst + (size_t)N * 4;
    int*   flag  = (int*)(denom + (size_t)N * 4);

    hipMemsetAsync(d_out, 0, (size_t)out_size * sizeof(float), stream);
    hipMemsetAsync(denom, 0, (size_t)N * 4 * sizeof(float), stream);

    detect_i64<<<1, 64, 0, stream>>>(ei, flag);
    proj_kernel<<<(N + NB - 1) / NB, 256, 0, stream>>>(x, W, a_src, a_dst, h_ws, ssrc, sdst, N);
    edge_scatter<<<(E + 3) / 4, 256, 0, stream>>>(ei, h_ws, ssrc, sdst, denom, out, flag, E);
    normalize_kernel<<<(N * 256 + 255) / 256, 256, 0, stream>>>(out, denom, N * 256);
}

// Round 2
// 403.358 us; speedup vs baseline: 1.9570x; 1.9570x over previous
//
#include <hip/hip_runtime.h>

#define HEADS 4
#define OUTF 64
#define INF 64
#define NB 16  // nodes per block in projection kernel

// --- detect whether edge_index arrived as int64 (odd dwords all zero) or int32 ---
__global__ __launch_bounds__(64) void detect_i64(const int* __restrict__ ei, int* __restrict__ flag) {
    if (threadIdx.x == 0) {
        int all0 = 1;
        #pragma unroll
        for (int i = 1; i < 64; i += 2) all0 &= (ei[i] == 0);
        *flag = all0;  // 1 -> int64 layout, 0 -> int32 layout
    }
}

// --- h[n,h,o] = sum_f x[n,f] * W[h,f,o]; s_src[n,h] = <h[n,h,:], a_src[h,:]>, same for dst ---
// block = 256 threads = 4 waves; wave w handles head w; lane = output feature o.
__global__ __launch_bounds__(256) void proj_kernel(
    const float* __restrict__ x, const float* __restrict__ W,
    const float* __restrict__ a_src, const float* __restrict__ a_dst,
    float* __restrict__ h_ws, float* __restrict__ ssrc, float* __restrict__ sdst,
    int nNodes)
{
    const int tid  = threadIdx.x;
    const int head = tid >> 6;
    const int o    = tid & 63;

    float w[64];
    const float* Wp = W + (size_t)head * (INF * OUTF) + o;
    #pragma unroll
    for (int f = 0; f < 64; ++f) w[f] = Wp[f * OUTF];

    const float asrc = a_src[tid];
    const float adst = a_dst[tid];

    const int n0 = blockIdx.x * NB;
    const int n1 = (n0 + NB < nNodes) ? (n0 + NB) : nNodes;
    for (int n = n0; n < n1; ++n) {
        const float* xr = x + (size_t)n * INF;  // wave-uniform address -> scalar loads
        float acc = 0.f;
        #pragma unroll
        for (int f = 0; f < 64; ++f) acc = fmaf(xr[f], w[f], acc);
        h_ws[(size_t)n * 256 + tid] = acc;

        float rs = acc * asrc;
        float rd = acc * adst;
        #pragma unroll
        for (int off = 32; off > 0; off >>= 1) {
            rs += __shfl_xor(rs, off);
            rd += __shfl_xor(rd, off);
        }
        if (o == 0) {
            ssrc[n * 4 + head] = rs;
            sdst[n * 4 + head] = rd;
        }
    }
}

// --- histogram of destination degrees ---
__global__ __launch_bounds__(256) void hist_kernel(
    const int* __restrict__ ei, const int* __restrict__ flag,
    int* __restrict__ cnt, int E)
{
    const int i = blockIdx.x * 256 + threadIdx.x;
    if (i >= E) return;
    const int dst = (*flag) ? ei[2 * ((size_t)E + i)] : ei[(size_t)E + i];
    atomicAdd(&cnt[dst], 1);
}

// --- single-block exclusive scan: row_start[0..N] and a mutable cursor copy ---
__global__ __launch_bounds__(1024) void scan_kernel(
    const int* __restrict__ cnt, int* __restrict__ row_start,
    int* __restrict__ cursor, int N)
{
    __shared__ int wsum[16];
    __shared__ int woff[17];
    const int tid  = threadIdx.x;
    const int lane = tid & 63;
    const int wv   = tid >> 6;
    int base = 0;
    if (tid == 0) row_start[0] = 0;
    for (int c0 = 0; c0 < N; c0 += 1024) {
        const int i = c0 + tid;
        const int v = (i < N) ? cnt[i] : 0;
        int incl = v;
        #pragma unroll
        for (int d = 1; d < 64; d <<= 1) {
            int t = __shfl_up(incl, d);
            if (lane >= d) incl += t;
        }
        if (lane == 63) wsum[wv] = incl;
        __syncthreads();
        if (tid == 0) {
            int a = 0;
            #pragma unroll
            for (int k = 0; k < 16; ++k) { woff[k] = a; a += wsum[k]; }
            woff[16] = a;
        }
        __syncthreads();
        const int g = base + woff[wv] + incl;  // inclusive prefix over [0, i]
        if (i < N) { row_start[i + 1] = g; cursor[i] = g - v; }
        base += woff[16];
        __syncthreads();  // protect wsum/woff before next chunk overwrites
    }
}

// --- place each edge's src into its dst's CSR slot ---
__global__ __launch_bounds__(256) void fill_kernel(
    const int* __restrict__ ei, const int* __restrict__ flag,
    int* __restrict__ cursor, int* __restrict__ csr_src, int E)
{
    const int i = blockIdx.x * 256 + threadIdx.x;
    if (i >= E) return;
    int src, dst;
    if (*flag) { src = ei[2 * (size_t)i]; dst = ei[2 * ((size_t)E + i)]; }
    else       { src = ei[i];             dst = ei[(size_t)E + i]; }
    const int pos = atomicAdd(&cursor[dst], 1);
    csr_src[pos] = src;
}

// --- one block per dst node: register-accumulate sum_e w_e * h[src_e], then one write ---
__global__ __launch_bounds__(256) void gather_kernel(
    const int* __restrict__ row_start, const int* __restrict__ csr_src,
    const float* __restrict__ h_ws, const float* __restrict__ ssrc,
    const float* __restrict__ sdst, float* __restrict__ out, int N)
{
    const int n    = blockIdx.x;
    const int tid  = threadIdx.x;
    const int head = tid >> 6;
    const int lane = tid & 63;
    const int start = row_start[n];
    const int end   = row_start[n + 1];
    const float sd  = sdst[n * 4 + head];

    float acc  = 0.f;
    float wsum = 0.f;
    for (int c = start; c < end; c += 64) {
        const int m = min(64, end - c);
        const int sv = (lane < m) ? csr_src[c + lane] : 0;  // one coalesced load per 64 edges
        for (int j = 0; j < m; ++j) {
            const int s = __shfl(sv, j);
            float e = ssrc[s * 4 + head] + sd;  // wave-broadcast L2 hit
            e = e >= 0.f ? e : 0.2f * e;
            const float w = __expf(e);
            acc  = fmaf(w, h_ws[(size_t)s * 256 + tid], acc);
            wsum += w;
        }
    }
    out[(size_t)n * 256 + tid] = acc / (wsum + 1e-16f);
}

extern "C" void kernel_launch(void* const* d_in, const int* in_sizes, int n_in,
                              void* d_out, int out_size, void* d_ws, size_t ws_size,
                              hipStream_t stream) {
    const float* x     = (const float*)d_in[0];
    const int*   ei    = (const int*)d_in[1];
    const float* W     = (const float*)d_in[2];
    const float* a_src = (const float*)d_in[3];
    const float* a_dst = (const float*)d_in[4];
    float*       out   = (float*)d_out;

    const int N = in_sizes[0] / INF;   // 50000
    const int E = in_sizes[1] / 2;     // 800000

    // workspace layout: h[N*256] | ssrc[N*4] | sdst[N*4] | cnt[N] | row_start[N+1] | cursor[N] | csr_src[E] | flag
    float* h_ws      = (float*)d_ws;
    float* ssrc      = h_ws + (size_t)N * 256;
    float* sdst      = ssrc + (size_t)N * 4;
    int*   cnt       = (int*)(sdst + (size_t)N * 4);
    int*   row_start = cnt + N;
    int*   cursor    = row_start + (N + 1);
    int*   csr_src   = cursor + N;
    int*   flag      = csr_src + E;

    hipMemsetAsync(cnt, 0, (size_t)N * sizeof(int), stream);

    detect_i64<<<1, 64, 0, stream>>>(ei, flag);
    proj_kernel<<<(N + NB - 1) / NB, 256, 0, stream>>>(x, W, a_src, a_dst, h_ws, ssrc, sdst, N);
    hist_kernel<<<(E + 255) / 256, 256, 0, stream>>>(ei, flag, cnt, E);
    scan_kernel<<<1, 1024, 0, stream>>>(cnt, row_start, cursor, N);
    fill_kernel<<<(E + 255) / 256, 256, 0, stream>>>(ei, flag, cursor, csr_src, E);
    gather_kernel<<<N, 256, 0, stream>>>(row_start, csr_src, h_ws, ssrc, sdst, out, N);
}

// Round 3
// 243.158 us; speedup vs baseline: 3.2463x; 1.6588x over previous
//
#include <hip/hip_runtime.h>

#define HEADS 4
#define OUTF 64
#define INF 64
#define NB 16  // nodes per block in projection kernel

// --- detect whether edge_index arrived as int64 (odd dwords all zero) or int32 ---
__global__ __launch_bounds__(64) void detect_i64(const int* __restrict__ ei, int* __restrict__ flag) {
    if (threadIdx.x == 0) {
        int all0 = 1;
        #pragma unroll
        for (int i = 1; i < 64; i += 2) all0 &= (ei[i] == 0);
        *flag = all0;  // 1 -> int64 layout, 0 -> int32 layout
    }
}

// --- h[n,h,o] = sum_f x[n,f]*W[h,f,o]; store h as bf16; s_src/s_dst in f32 ---
// block = 256 threads = 4 waves; wave w handles head w; lane = output feature o.
__global__ __launch_bounds__(256) void proj_kernel(
    const float* __restrict__ x, const float* __restrict__ W,
    const float* __restrict__ a_src, const float* __restrict__ a_dst,
    ushort* __restrict__ h_bf, float* __restrict__ ssrc, float* __restrict__ sdst,
    int nNodes)
{
    const int tid  = threadIdx.x;
    const int head = tid >> 6;
    const int o    = tid & 63;

    float w[64];
    const float* Wp = W + (size_t)head * (INF * OUTF) + o;
    #pragma unroll
    for (int f = 0; f < 64; ++f) w[f] = Wp[f * OUTF];

    const float asrc = a_src[tid];
    const float adst = a_dst[tid];

    const int n0 = blockIdx.x * NB;
    const int n1 = (n0 + NB < nNodes) ? (n0 + NB) : nNodes;
    for (int n = n0; n < n1; ++n) {
        const float* xr = x + (size_t)n * INF;  // wave-uniform -> scalar loads
        float acc = 0.f;
        #pragma unroll
        for (int f = 0; f < 64; ++f) acc = fmaf(xr[f], w[f], acc);

        // bf16 round-to-nearest-even
        const unsigned u = __float_as_uint(acc);
        h_bf[(size_t)n * 256 + tid] = (ushort)((u + 0x7fffu + ((u >> 16) & 1u)) >> 16);

        float rs = acc * asrc;
        float rd = acc * adst;
        #pragma unroll
        for (int off = 32; off > 0; off >>= 1) {
            rs += __shfl_xor(rs, off);
            rd += __shfl_xor(rd, off);
        }
        if (o == 0) {
            ssrc[n * 4 + head] = rs;
            sdst[n * 4 + head] = rd;
        }
    }
}

// --- histogram of destination degrees ---
__global__ __launch_bounds__(256) void hist_kernel(
    const int* __restrict__ ei, const int* __restrict__ flag,
    int* __restrict__ cnt, int E)
{
    const int i = blockIdx.x * 256 + threadIdx.x;
    if (i >= E) return;
    const int dst = (*flag) ? ei[2 * ((size_t)E + i)] : ei[(size_t)E + i];
    atomicAdd(&cnt[dst], 1);
}

// --- parallel scan, stage 1: per-block (2048 elems) partial sums ---
__global__ __launch_bounds__(256) void scan_partial(
    const int* __restrict__ cnt, int* __restrict__ bsum, int N)
{
    const int t = threadIdx.x, lane = t & 63, wv = t >> 6;
    const int i0 = blockIdx.x * 2048 + t * 8;
    int s = 0;
    #pragma unroll
    for (int k = 0; k < 8; ++k) if (i0 + k < N) s += cnt[i0 + k];
    #pragma unroll
    for (int off = 32; off > 0; off >>= 1) s += __shfl_xor(s, off);
    __shared__ int ws[4];
    if (lane == 0) ws[wv] = s;
    __syncthreads();
    if (t == 0) bsum[blockIdx.x] = ws[0] + ws[1] + ws[2] + ws[3];
}

// --- stage 2: exclusive scan of block sums (nb <= 64, trivial serial) ---
__global__ __launch_bounds__(64) void scan_bsum(int* __restrict__ bsum, int nb)
{
    if (threadIdx.x == 0) {
        int run = 0;
        for (int b = 0; b < nb; ++b) { int v = bsum[b]; bsum[b] = run; run += v; }
    }
}

// --- stage 3: per-block re-scan with offset -> row_start[0..N], cursor[0..N) ---
__global__ __launch_bounds__(256) void scan_final(
    const int* __restrict__ cnt, const int* __restrict__ bsum,
    int* __restrict__ row_start, int* __restrict__ cursor, int N)
{
    const int t = threadIdx.x, lane = t & 63, wv = t >> 6;
    const int i0 = blockIdx.x * 2048 + t * 8;
    int v[8], s = 0;
    #pragma unroll
    for (int k = 0; k < 8; ++k) { v[k] = (i0 + k < N) ? cnt[i0 + k] : 0; s += v[k]; }
    int incl = s;
    #pragma unroll
    for (int d = 1; d < 64; d <<= 1) {
        int tm = __shfl_up(incl, d);
        if (lane >= d) incl += tm;
    }
    __shared__ int ws[4];
    if (lane == 63) ws[wv] = incl;
    __syncthreads();
    int woff = 0;
    for (int k = 0; k < wv; ++k) woff += ws[k];
    int run = bsum[blockIdx.x] + woff + incl - s;  // exclusive prefix at i0
    #pragma unroll
    for (int k = 0; k < 8; ++k) {
        if (i0 + k < N) { cursor[i0 + k] = run; row_start[i0 + k + 1] = run + v[k]; }
        run += v[k];
    }
    if (blockIdx.x == 0 && t == 0) row_start[0] = 0;
}

// --- place each edge's src into its dst's CSR slot ---
__global__ __launch_bounds__(256) void fill_kernel(
    const int* __restrict__ ei, const int* __restrict__ flag,
    int* __restrict__ cursor, int* __restrict__ csr_src, int E)
{
    const int i = blockIdx.x * 256 + threadIdx.x;
    if (i >= E) return;
    int src, dst;
    if (*flag) { src = ei[2 * (size_t)i]; dst = ei[2 * ((size_t)E + i)]; }
    else       { src = ei[i];             dst = ei[(size_t)E + i]; }
    const int pos = atomicAdd(&cursor[dst], 1);
    csr_src[pos] = src;
}

// --- one WAVE per dst node; lane covers 4 output features (uint2 bf16x4 loads) ---
__global__ __launch_bounds__(256) void gather_kernel(
    const int* __restrict__ row_start, const int* __restrict__ csr_src,
    const ushort* __restrict__ h_bf, const float* __restrict__ ssrc,
    const float* __restrict__ sdst, float* __restrict__ out, int N)
{
    const int tid  = threadIdx.x;
    const int lane = tid & 63;
    const int n    = blockIdx.x * 4 + (tid >> 6);
    if (n >= N) return;
    const int head = lane >> 4;  // features lane*4..lane*4+3 all in this head
    const int start = row_start[n];
    const int end   = row_start[n + 1];
    const float sd  = sdst[n * 4 + head];

    float a0 = 0.f, a1 = 0.f, a2 = 0.f, a3 = 0.f, wsum = 0.f;
    int c = start;
    for (; c + 64 <= end; c += 64) {
        const int sv = csr_src[c + lane];
        #pragma unroll 4
        for (int j = 0; j < 64; ++j) {
            const int s = __shfl(sv, j);
            float e = ssrc[s * 4 + head] + sd;
            e = e >= 0.f ? e : 0.2f * e;
            const float w = __expf(e);
            const uint2 hv = *reinterpret_cast<const uint2*>(h_bf + ((size_t)s << 8) + (lane << 2));
            a0 = fmaf(w, __uint_as_float(hv.x << 16), a0);
            a1 = fmaf(w, __uint_as_float(hv.x & 0xffff0000u), a1);
            a2 = fmaf(w, __uint_as_float(hv.y << 16), a2);
            a3 = fmaf(w, __uint_as_float(hv.y & 0xffff0000u), a3);
            wsum += w;
        }
    }
    const int rem = end - c;
    if (rem > 0) {
        const int sv = (lane < rem) ? csr_src[c + lane] : 0;
        for (int j = 0; j < rem; ++j) {
            const int s = __shfl(sv, j);
            float e = ssrc[s * 4 + head] + sd;
            e = e >= 0.f ? e : 0.2f * e;
            const float w = __expf(e);
            const uint2 hv = *reinterpret_cast<const uint2*>(h_bf + ((size_t)s << 8) + (lane << 2));
            a0 = fmaf(w, __uint_as_float(hv.x << 16), a0);
            a1 = fmaf(w, __uint_as_float(hv.x & 0xffff0000u), a1);
            a2 = fmaf(w, __uint_as_float(hv.y << 16), a2);
            a3 = fmaf(w, __uint_as_float(hv.y & 0xffff0000u), a3);
            wsum += w;
        }
    }
    const float inv = 1.f / (wsum + 1e-16f);
    float4 o;
    o.x = a0 * inv; o.y = a1 * inv; o.z = a2 * inv; o.w = a3 * inv;
    *reinterpret_cast<float4*>(out + ((size_t)n << 8) + (lane << 2)) = o;
}

extern "C" void kernel_launch(void* const* d_in, const int* in_sizes, int n_in,
                              void* d_out, int out_size, void* d_ws, size_t ws_size,
                              hipStream_t stream) {
    const float* x     = (const float*)d_in[0];
    const int*   ei    = (const int*)d_in[1];
    const float* W     = (const float*)d_in[2];
    const float* a_src = (const float*)d_in[3];
    const float* a_dst = (const float*)d_in[4];
    float*       out   = (float*)d_out;

    const int N = in_sizes[0] / INF;   // 50000
    const int E = in_sizes[1] / 2;     // 800000

    // workspace layout: h_bf[N*256 ushort] | ssrc[N*4] | sdst[N*4] | cnt[N] | row_start[N+1] | cursor[N] | csr_src[E] | bsum[64] | flag
    ushort* h_bf     = (ushort*)d_ws;
    float* ssrc      = (float*)(h_bf + (size_t)N * 256);
    float* sdst      = ssrc + (size_t)N * 4;
    int*   cnt       = (int*)(sdst + (size_t)N * 4);
    int*   row_start = cnt + N;
    int*   cursor    = row_start + (N + 1);
    int*   csr_src   = cursor + N;
    int*   bsum      = csr_src + E;
    int*   flag      = bsum + 64;

    const int nb = (N + 2047) / 2048;

    hipMemsetAsync(cnt, 0, (size_t)N * sizeof(int), stream);

    detect_i64<<<1, 64, 0, stream>>>(ei, flag);
    proj_kernel<<<(N + NB - 1) / NB, 256, 0, stream>>>(x, W, a_src, a_dst, h_bf, ssrc, sdst, N);
    hist_kernel<<<(E + 255) / 256, 256, 0, stream>>>(ei, flag, cnt, E);
    scan_partial<<<nb, 256, 0, stream>>>(cnt, bsum, N);
    scan_bsum<<<1, 64, 0, stream>>>(bsum, nb);
    scan_final<<<nb, 256, 0, stream>>>(cnt, bsum, row_start, cursor, N);
    fill_kernel<<<(E + 255) / 256, 256, 0, stream>>>(ei, flag, cursor, csr_src, E);
    gather_kernel<<<(N + 3) / 4, 256, 0, stream>>>(row_start, csr_src, h_bf, ssrc, sdst, out, N);
}

// Round 4
// 207.930 us; speedup vs baseline: 3.7962x; 1.1694x over previous
//
#include <hip/hip_runtime.h>

#define HEADS 4
#define OUTF 64
#define INF 64
#define NB 16  // nodes per block in projection kernel

// --- detect whether edge_index arrived as int64 (odd dwords all zero) or int32 ---
__global__ __launch_bounds__(64) void detect_i64(const int* __restrict__ ei, int* __restrict__ flag) {
    if (threadIdx.x == 0) {
        int all0 = 1;
        #pragma unroll
        for (int i = 1; i < 64; i += 2) all0 &= (ei[i] == 0);
        *flag = all0;  // 1 -> int64 layout, 0 -> int32 layout
    }
}

// --- fused: dst-degree histogram + h = x@W (bf16 out) + s_src/s_dst reductions ---
// block = 256 threads = 4 waves; wave w handles head w; lane = output feature o.
// W column pinned in VGPRs (asm pin + launch_bounds(256,4) for the 128-VGPR budget).
__global__ __launch_bounds__(256, 4) void proj_kernel(
    const float* __restrict__ x, const float* __restrict__ W,
    const float* __restrict__ a_src, const float* __restrict__ a_dst,
    ushort* __restrict__ h_bf, float* __restrict__ ssrc, float* __restrict__ sdst,
    const int* __restrict__ ei, const int* __restrict__ flag,
    int* __restrict__ cnt, int nNodes, int E)
{
    const int tid  = threadIdx.x;
    const int head = tid >> 6;
    const int o    = tid & 63;

    // fused histogram: this block's slice of edges (overlaps with W preload latency)
    const int estride = gridDim.x * 256;
    const int i64 = *flag;
    for (int i = blockIdx.x * 256 + tid; i < E; i += estride) {
        const int dst = i64 ? ei[2 * ((size_t)E + i)] : ei[(size_t)E + i];
        atomicAdd(&cnt[dst], 1);
    }

    float w[64];
    const float* Wp = W + (size_t)head * (INF * OUTF) + o;
    #pragma unroll
    for (int f = 0; f < 64; ++f) w[f] = Wp[f * OUTF];
    #pragma unroll
    for (int f = 0; f < 64; ++f) asm volatile("" : "+v"(w[f]));  // pin in VGPRs

    const float asrc = a_src[tid];
    const float adst = a_dst[tid];

    const int n0 = blockIdx.x * NB;
    const int n1 = (n0 + NB < nNodes) ? (n0 + NB) : nNodes;
    int n = n0;
    for (; n + 1 < n1; n += 2) {
        const float* xa = x + (size_t)n * INF;        // wave-uniform -> scalar loads
        const float* xb = xa + INF;
        float a0 = 0.f, a1 = 0.f, a2 = 0.f, a3 = 0.f;
        float b0 = 0.f, b1 = 0.f, b2 = 0.f, b3 = 0.f;
        #pragma unroll
        for (int f = 0; f < 64; f += 4) {             // 8 independent 16-deep chains
            a0 = fmaf(xa[f + 0], w[f + 0], a0);
            a1 = fmaf(xa[f + 1], w[f + 1], a1);
            a2 = fmaf(xa[f + 2], w[f + 2], a2);
            a3 = fmaf(xa[f + 3], w[f + 3], a3);
            b0 = fmaf(xb[f + 0], w[f + 0], b0);
            b1 = fmaf(xb[f + 1], w[f + 1], b1);
            b2 = fmaf(xb[f + 2], w[f + 2], b2);
            b3 = fmaf(xb[f + 3], w[f + 3], b3);
        }
        const float accA = (a0 + a1) + (a2 + a3);
        const float accB = (b0 + b1) + (b2 + b3);

        const unsigned ua = __float_as_uint(accA);
        const unsigned ub = __float_as_uint(accB);
        h_bf[(size_t)n * 256 + tid]       = (ushort)((ua + 0x7fffu + ((ua >> 16) & 1u)) >> 16);
        h_bf[(size_t)(n + 1) * 256 + tid] = (ushort)((ub + 0x7fffu + ((ub >> 16) & 1u)) >> 16);

        float rsA = accA * asrc, rdA = accA * adst;
        float rsB = accB * asrc, rdB = accB * adst;
        #pragma unroll
        for (int off = 32; off > 0; off >>= 1) {      // 4 interleaved reduce chains
            rsA += __shfl_xor(rsA, off);
            rdA += __shfl_xor(rdA, off);
            rsB += __shfl_xor(rsB, off);
            rdB += __shfl_xor(rdB, off);
        }
        if (o == 0) {
            ssrc[n * 4 + head] = rsA;  sdst[n * 4 + head] = rdA;
            ssrc[(n + 1) * 4 + head] = rsB;  sdst[(n + 1) * 4 + head] = rdB;
        }
    }
    for (; n < n1; ++n) {  // odd tail
        const float* xr = x + (size_t)n * INF;
        float a0 = 0.f, a1 = 0.f, a2 = 0.f, a3 = 0.f;
        #pragma unroll
        for (int f = 0; f < 64; f += 4) {
            a0 = fmaf(xr[f + 0], w[f + 0], a0);
            a1 = fmaf(xr[f + 1], w[f + 1], a1);
            a2 = fmaf(xr[f + 2], w[f + 2], a2);
            a3 = fmaf(xr[f + 3], w[f + 3], a3);
        }
        const float acc = (a0 + a1) + (a2 + a3);
        const unsigned u = __float_as_uint(acc);
        h_bf[(size_t)n * 256 + tid] = (ushort)((u + 0x7fffu + ((u >> 16) & 1u)) >> 16);
        float rs = acc * asrc, rd = acc * adst;
        #pragma unroll
        for (int off = 32; off > 0; off >>= 1) {
            rs += __shfl_xor(rs, off);
            rd += __shfl_xor(rd, off);
        }
        if (o == 0) { ssrc[n * 4 + head] = rs; sdst[n * 4 + head] = rd; }
    }
}

// --- parallel scan, stage 1: per-block (2048 elems) partial sums ---
__global__ __launch_bounds__(256) void scan_partial(
    const int* __restrict__ cnt, int* __restrict__ bsum, int N)
{
    const int t = threadIdx.x, lane = t & 63, wv = t >> 6;
    const int i0 = blockIdx.x * 2048 + t * 8;
    int s = 0;
    #pragma unroll
    for (int k = 0; k < 8; ++k) if (i0 + k < N) s += cnt[i0 + k];
    #pragma unroll
    for (int off = 32; off > 0; off >>= 1) s += __shfl_xor(s, off);
    __shared__ int ws[4];
    if (lane == 0) ws[wv] = s;
    __syncthreads();
    if (t == 0) bsum[blockIdx.x] = ws[0] + ws[1] + ws[2] + ws[3];
}

// --- stage 2: exclusive scan of block sums (nb <= 64, trivial serial) ---
__global__ __launch_bounds__(64) void scan_bsum(int* __restrict__ bsum, int nb)
{
    if (threadIdx.x == 0) {
        int run = 0;
        for (int b = 0; b < nb; ++b) { int v = bsum[b]; bsum[b] = run; run += v; }
    }
}

// --- stage 3: per-block re-scan with offset -> row_start[0..N], cursor[0..N) ---
__global__ __launch_bounds__(256) void scan_final(
    const int* __restrict__ cnt, const int* __restrict__ bsum,
    int* __restrict__ row_start, int* __restrict__ cursor, int N)
{
    const int t = threadIdx.x, lane = t & 63, wv = t >> 6;
    const int i0 = blockIdx.x * 2048 + t * 8;
    int v[8], s = 0;
    #pragma unroll
    for (int k = 0; k < 8; ++k) { v[k] = (i0 + k < N) ? cnt[i0 + k] : 0; s += v[k]; }
    int incl = s;
    #pragma unroll
    for (int d = 1; d < 64; d <<= 1) {
        int tm = __shfl_up(incl, d);
        if (lane >= d) incl += tm;
    }
    __shared__ int ws[4];
    if (lane == 63) ws[wv] = incl;
    __syncthreads();
    int woff = 0;
    for (int k = 0; k < wv; ++k) woff += ws[k];
    int run = bsum[blockIdx.x] + woff + incl - s;  // exclusive prefix at i0
    #pragma unroll
    for (int k = 0; k < 8; ++k) {
        if (i0 + k < N) { cursor[i0 + k] = run; row_start[i0 + k + 1] = run + v[k]; }
        run += v[k];
    }
    if (blockIdx.x == 0 && t == 0) row_start[0] = 0;
}

// --- place each edge's src into its dst's CSR slot ---
__global__ __launch_bounds__(256) void fill_kernel(
    const int* __restrict__ ei, const int* __restrict__ flag,
    int* __restrict__ cursor, int* __restrict__ csr_src, int E)
{
    const int i = blockIdx.x * 256 + threadIdx.x;
    if (i >= E) return;
    int src, dst;
    if (*flag) { src = ei[2 * (size_t)i]; dst = ei[2 * ((size_t)E + i)]; }
    else       { src = ei[i];             dst = ei[(size_t)E + i]; }
    const int pos = atomicAdd(&cursor[dst], 1);
    csr_src[pos] = src;
}

// --- one WAVE per dst node; lane covers 4 output features (uint2 bf16x4 loads) ---
__global__ __launch_bounds__(256) void gather_kernel(
    const int* __restrict__ row_start, const int* __restrict__ csr_src,
    const ushort* __restrict__ h_bf, const float* __restrict__ ssrc,
    const float* __restrict__ sdst, float* __restrict__ out, int N)
{
    const int tid  = threadIdx.x;
    const int lane = tid & 63;
    const int n    = blockIdx.x * 4 + (tid >> 6);
    if (n >= N) return;
    const int head = lane >> 4;  // features lane*4..lane*4+3 all in this head
    const int start = row_start[n];
    const int end   = row_start[n + 1];
    const float sd  = sdst[n * 4 + head];

    float a0 = 0.f, a1 = 0.f, a2 = 0.f, a3 = 0.f, wsum = 0.f;
    int c = start;
    for (; c + 64 <= end; c += 64) {
        const int sv = csr_src[c + lane];
        #pragma unroll 4
        for (int j = 0; j < 64; ++j) {
            const int s = __shfl(sv, j);
            float e = ssrc[s * 4 + head] + sd;
            e = e >= 0.f ? e : 0.2f * e;
            const float w = __expf(e);
            const uint2 hv = *reinterpret_cast<const uint2*>(h_bf + ((size_t)s << 8) + (lane << 2));
            a0 = fmaf(w, __uint_as_float(hv.x << 16), a0);
            a1 = fmaf(w, __uint_as_float(hv.x & 0xffff0000u), a1);
            a2 = fmaf(w, __uint_as_float(hv.y << 16), a2);
            a3 = fmaf(w, __uint_as_float(hv.y & 0xffff0000u), a3);
            wsum += w;
        }
    }
    const int rem = end - c;
    if (rem > 0) {
        const int sv = (lane < rem) ? csr_src[c + lane] : 0;
        for (int j = 0; j < rem; ++j) {
            const int s = __shfl(sv, j);
            float e = ssrc[s * 4 + head] + sd;
            e = e >= 0.f ? e : 0.2f * e;
            const float w = __expf(e);
            const uint2 hv = *reinterpret_cast<const uint2*>(h_bf + ((size_t)s << 8) + (lane << 2));
            a0 = fmaf(w, __uint_as_float(hv.x << 16), a0);
            a1 = fmaf(w, __uint_as_float(hv.x & 0xffff0000u), a1);
            a2 = fmaf(w, __uint_as_float(hv.y << 16), a2);
            a3 = fmaf(w, __uint_as_float(hv.y & 0xffff0000u), a3);
            wsum += w;
        }
    }
    const float inv = 1.f / (wsum + 1e-16f);
    float4 o;
    o.x = a0 * inv; o.y = a1 * inv; o.z = a2 * inv; o.w = a3 * inv;
    *reinterpret_cast<float4*>(out + ((size_t)n << 8) + (lane << 2)) = o;
}

extern "C" void kernel_launch(void* const* d_in, const int* in_sizes, int n_in,
                              void* d_out, int out_size, void* d_ws, size_t ws_size,
                              hipStream_t stream) {
    const float* x     = (const float*)d_in[0];
    const int*   ei    = (const int*)d_in[1];
    const float* W     = (const float*)d_in[2];
    const float* a_src = (const float*)d_in[3];
    const float* a_dst = (const float*)d_in[4];
    float*       out   = (float*)d_out;

    const int N = in_sizes[0] / INF;   // 50000
    const int E = in_sizes[1] / 2;     // 800000

    // workspace: h_bf[N*256 ushort] | ssrc[N*4] | sdst[N*4] | cnt[N] | row_start[N+1] | cursor[N] | csr_src[E] | bsum[64] | flag
    ushort* h_bf     = (ushort*)d_ws;
    float* ssrc      = (float*)(h_bf + (size_t)N * 256);
    float* sdst      = ssrc + (size_t)N * 4;
    int*   cnt       = (int*)(sdst + (size_t)N * 4);
    int*   row_start = cnt + N;
    int*   cursor    = row_start + (N + 1);
    int*   csr_src   = cursor + N;
    int*   bsum      = csr_src + E;
    int*   flag      = bsum + 64;

    const int nb = (N + 2047) / 2048;

    hipMemsetAsync(cnt, 0, (size_t)N * sizeof(int), stream);

    detect_i64<<<1, 64, 0, stream>>>(ei, flag);
    proj_kernel<<<(N + NB - 1) / NB, 256, 0, stream>>>(x, W, a_src, a_dst, h_bf, ssrc, sdst, ei, flag, cnt, N, E);
    scan_partial<<<nb, 256, 0, stream>>>(cnt, bsum, N);
    scan_bsum<<<1, 64, 0, stream>>>(bsum, nb);
    scan_final<<<nb, 256, 0, stream>>>(cnt, bsum, row_start, cursor, N);
    fill_kernel<<<(E + 255) / 256, 256, 0, stream>>>(ei, flag, cursor, csr_src, E);
    gather_kernel<<<(N + 3) / 4, 256, 0, stream>>>(row_start, csr_src, h_bf, ssrc, sdst, out, N);
}